// Round 1
// baseline (2028.851 us; speedup 1.0000x reference)
//
#include <hip/hip_runtime.h>
#include <hip/hip_bf16.h>

#define NNODES 1000000
#define NB 2000
#define BN_EPS 1e-5f

// ---------------- kernel 1: graph boundaries + zero BN stats ----------------
__global__ __launch_bounds__(256) void k_bounds(const int* __restrict__ batch,
                                                int* __restrict__ start,
                                                float* __restrict__ stats) {
    int g = blockIdx.x * 256 + threadIdx.x;
    if (g < 256) stats[g] = 0.f;          // [0:128]=sum, [128:256]=sumsq
    if (g > NB) return;
    if (g == NB) { start[g] = NNODES; return; }
    int lo = 0, hi = NNODES;
    while (lo < hi) {
        int mid = (lo + hi) >> 1;
        if (batch[mid] < g) lo = mid + 1; else hi = mid;
    }
    start[g] = lo;
}

// ---------------- kernel 2: h1 = relu(x0 @ W0 + b0), store bf16 [64][N] ------
__global__ __launch_bounds__(256) void k_h1(const float* __restrict__ pp,
                                            const float* __restrict__ W0,
                                            const float* __restrict__ b0,
                                            __hip_bfloat16* __restrict__ h1T) {
    __shared__ float w0t[16 * 64];  // [j][k]
    __shared__ float b0s[64];
    int tid = threadIdx.x;
    for (int idx = tid; idx < 1024; idx += 256) {
        int k = idx >> 6, j = idx & 63;
        w0t[j * 16 + k] = W0[idx];
    }
    if (tid < 64) b0s[tid] = b0[tid];
    __syncthreads();
    int n = blockIdx.x * 256 + tid;
    if (n >= NNODES) return;
    float xk[16];
    const float2* pp2 = (const float2*)pp;
    #pragma unroll
    for (int f = 0; f < 8; ++f) {
        float2 v = pp2[(size_t)f * NNODES + n];   // pp[f][n][0..1]
        xk[2 * f] = v.x; xk[2 * f + 1] = v.y;
    }
    for (int j = 0; j < 64; ++j) {
        float acc = b0s[j];
        const float4* wr = (const float4*)&w0t[j * 16];
        #pragma unroll
        for (int k4 = 0; k4 < 4; ++k4) {
            float4 w = wr[k4];
            acc += xk[4*k4+0]*w.x + xk[4*k4+1]*w.y + xk[4*k4+2]*w.z + xk[4*k4+3]*w.w;
        }
        h1T[(size_t)j * NNODES + n] = __float2bfloat16(fmaxf(acc, 0.f));
    }
}

// ------------- kernel 3/5: xm[g] = mean_g(hT) @ lw   (block per graph) -------
__global__ __launch_bounds__(256) void k_xm(const __hip_bfloat16* __restrict__ hT,
                                            const int* __restrict__ start,
                                            const float* __restrict__ lw,
                                            float* __restrict__ xm, int J) {
    __shared__ float meanv[64];
    int g = blockIdx.x;
    int s = start[g], e = start[g + 1];
    float cntf = fmaxf((float)(e - s), 1.f);
    int tid = threadIdx.x;
    int wave = tid >> 6, lane = tid & 63;
    for (int j = wave * 16; j < wave * 16 + 16; ++j) {  // 4 waves x 16 feats
        float sum = 0.f;
        for (int n = s + lane; n < e; n += 64)
            sum += __bfloat162float(hT[(size_t)j * NNODES + n]);
        #pragma unroll
        for (int off = 32; off; off >>= 1) sum += __shfl_xor(sum, off, 64);
        if (lane == 0) meanv[j] = sum / cntf;
    }
    __syncthreads();
    for (int j = tid; j < J; j += 256) {
        float acc = 0.f;
        #pragma unroll 8
        for (int k = 0; k < 64; ++k) acc += meanv[k] * lw[k * J + j];
        xm[(size_t)g * J + j] = acc;
    }
}

// ------- kernel 4: h2 = relu(h1 @ g1_w + g1_b - xm1[batch]), bf16 [64][N] ----
__global__ __launch_bounds__(256) void k_layer1(const __hip_bfloat16* __restrict__ h1T,
                                                const int* __restrict__ batch,
                                                const float* __restrict__ g1w,
                                                const float* __restrict__ g1b,
                                                const float* __restrict__ xm1,
                                                __hip_bfloat16* __restrict__ h2T) {
    __shared__ float wt[64 * 64];  // [j][k], 16 KB
    int tid = threadIdx.x;
    for (int idx = tid; idx < 4096; idx += 256) {
        int k = idx >> 6, j = idx & 63;
        wt[j * 64 + k] = g1w[idx];
    }
    __syncthreads();
    int n = blockIdx.x * 256 + tid;
    if (n >= NNODES) return;
    float h[64];
    #pragma unroll
    for (int k = 0; k < 64; ++k)
        h[k] = __bfloat162float(h1T[(size_t)k * NNODES + n]);
    int g = batch[n];
    const float* xr = &xm1[(size_t)g * 64];
    for (int j = 0; j < 64; ++j) {
        float acc = g1b[j] - xr[j];
        const float4* wr = (const float4*)&wt[j * 64];
        #pragma unroll
        for (int k4 = 0; k4 < 16; ++k4) {
            float4 w = wr[k4];
            acc += h[4*k4+0]*w.x + h[4*k4+1]*w.y + h[4*k4+2]*w.z + h[4*k4+3]*w.w;
        }
        h2T[(size_t)j * NNODES + n] = __float2bfloat16(fmaxf(acc, 0.f));
    }
}

// ------- kernel 6: v = relu(h2 @ g2_w + g2_b - xm2[batch]), bf16 [128][N] ----
__global__ __launch_bounds__(256) void k_layer2(const __hip_bfloat16* __restrict__ h2T,
                                                const int* __restrict__ batch,
                                                const float* __restrict__ g2w,
                                                const float* __restrict__ g2b,
                                                const float* __restrict__ xm2,
                                                __hip_bfloat16* __restrict__ vT) {
    __shared__ float wt[128 * 64];  // [j][k], 32 KB
    int tid = threadIdx.x;
    for (int idx = tid; idx < 8192; idx += 256) {
        int k = idx >> 7, j = idx & 127;
        wt[j * 64 + k] = g2w[idx];
    }
    __syncthreads();
    int n = blockIdx.x * 256 + tid;
    if (n >= NNODES) return;
    float h[64];
    #pragma unroll
    for (int k = 0; k < 64; ++k)
        h[k] = __bfloat162float(h2T[(size_t)k * NNODES + n]);
    int g = batch[n];
    const float* xr = &xm2[(size_t)g * 128];
    for (int j = 0; j < 128; ++j) {
        float acc = g2b[j] - xr[j];
        const float4* wr = (const float4*)&wt[j * 64];
        #pragma unroll
        for (int k4 = 0; k4 < 16; ++k4) {
            float4 w = wr[k4];
            acc += h[4*k4+0]*w.x + h[4*k4+1]*w.y + h[4*k4+2]*w.z + h[4*k4+3]*w.w;
        }
        vT[(size_t)j * NNODES + n] = __float2bfloat16(fmaxf(acc, 0.f));
    }
}

// ---------------- kernel 7: BN sum / sumsq per feature -----------------------
__global__ __launch_bounds__(256) void k_bnstats(const __hip_bfloat16* __restrict__ vT,
                                                 float* __restrict__ stats) {
    int j = blockIdx.x;
    int tid = threadIdx.x;
    const __hip_bfloat16* row = &vT[(size_t)j * NNODES];
    float s = 0.f, sq = 0.f;
    for (int n = blockIdx.y * 256 + tid; n < NNODES; n += gridDim.y * 256) {
        float v = __bfloat162float(row[n]);
        s += v; sq += v * v;
    }
    #pragma unroll
    for (int off = 32; off; off >>= 1) {
        s += __shfl_xor(s, off, 64);
        sq += __shfl_xor(sq, off, 64);
    }
    __shared__ float ps[4], pq[4];
    int wave = tid >> 6, lane = tid & 63;
    if (lane == 0) { ps[wave] = s; pq[wave] = sq; }
    __syncthreads();
    if (tid == 0) {
        atomicAdd(&stats[j], ps[0] + ps[1] + ps[2] + ps[3]);
        atomicAdd(&stats[128 + j], pq[0] + pq[1] + pq[2] + pq[3]);
    }
}

// ---------------- kernel 8: finalize scale/shift -----------------------------
__global__ void k_bnfinal(const float* __restrict__ stats,
                          const float* __restrict__ gamma,
                          const float* __restrict__ beta,
                          float* __restrict__ ss) {
    int j = threadIdx.x;
    if (j < 128) {
        float mean = stats[j] * (1.f / NNODES);
        float var = stats[128 + j] * (1.f / NNODES) - mean * mean;
        float sc = gamma[j] * rsqrtf(var + BN_EPS);
        ss[j] = sc;
        ss[128 + j] = beta[j] - mean * sc;
    }
}

// ---------------- kernel 9: out = x + scale*v + shift (transpose tile) -------
__global__ __launch_bounds__(256) void k_out(const __hip_bfloat16* __restrict__ vT,
                                             const float* __restrict__ x,
                                             const float* __restrict__ ss,
                                             float* __restrict__ out) {
    __shared__ float tile[128][65];
    __shared__ float sc[128], sh[128];
    int tid = threadIdx.x;
    if (tid < 128) { sc[tid] = ss[tid]; sh[tid] = ss[128 + tid]; }
    int n0 = blockIdx.x * 64;
    #pragma unroll 4
    for (int i = 0; i < 32; ++i) {
        int idx = tid + 256 * i;
        int c = idx >> 6, nn = idx & 63;
        tile[c][nn] = __bfloat162float(vT[(size_t)c * NNODES + n0 + nn]);
    }
    __syncthreads();
    #pragma unroll 4
    for (int i = 0; i < 32; ++i) {
        int idx = tid + 256 * i;
        int nn = idx >> 7, c = idx & 127;
        size_t off = (size_t)(n0 + nn) * 128 + c;
        out[off] = x[off] + sc[c] * tile[c][nn] + sh[c];
    }
}

extern "C" void kernel_launch(void* const* d_in, const int* in_sizes, int n_in,
                              void* d_out, int out_size, void* d_ws, size_t ws_size,
                              hipStream_t stream) {
    const float* x     = (const float*)d_in[0];
    const float* pp    = (const float*)d_in[1];
    const int*   batch = (const int*)d_in[2];
    const float* W0    = (const float*)d_in[3];
    const float* b0    = (const float*)d_in[4];
    const float* g1w   = (const float*)d_in[5];
    const float* g1b   = (const float*)d_in[6];
    const float* l1w   = (const float*)d_in[7];
    const float* g2w   = (const float*)d_in[8];
    const float* g2b   = (const float*)d_in[9];
    const float* l2w   = (const float*)d_in[10];
    const float* bng   = (const float*)d_in[11];
    const float* bnb   = (const float*)d_in[12];
    float* out = (float*)d_out;

    char* ws = (char*)d_ws;
    size_t o = 0;
    __hip_bfloat16* h1T = (__hip_bfloat16*)(ws + o); o += (size_t)64 * NNODES * 2;
    __hip_bfloat16* h2T = (__hip_bfloat16*)(ws + o); o += (size_t)64 * NNODES * 2;
    __hip_bfloat16* vT  = (__hip_bfloat16*)(ws + o); o += (size_t)128 * NNODES * 2;
    int*   start = (int*)(ws + o);   o += 16384;
    float* xm1   = (float*)(ws + o); o += (size_t)NB * 64 * 4;
    float* xm2   = (float*)(ws + o); o += (size_t)NB * 128 * 4;
    float* stats = (float*)(ws + o); o += 1024;
    float* ss    = (float*)(ws + o); o += 1024;

    int nblk = (NNODES + 255) / 256;
    k_bounds<<<8, 256, 0, stream>>>(batch, start, stats);
    k_h1<<<nblk, 256, 0, stream>>>(pp, W0, b0, h1T);
    k_xm<<<NB, 256, 0, stream>>>(h1T, start, l1w, xm1, 64);
    k_layer1<<<nblk, 256, 0, stream>>>(h1T, batch, g1w, g1b, xm1, h2T);
    k_xm<<<NB, 256, 0, stream>>>(h2T, start, l2w, xm2, 128);
    k_layer2<<<nblk, 256, 0, stream>>>(h2T, batch, g2w, g2b, xm2, vT);
    k_bnstats<<<dim3(128, 16), 256, 0, stream>>>(vT, stats);
    k_bnfinal<<<1, 128, 0, stream>>>(stats, bng, bnb, ss);
    k_out<<<NNODES / 64, 256, 0, stream>>>(vT, x, ss, out);
}